// Round 15
// baseline (1717.334 us; speedup 1.0000x reference)
//
#include <hip/hip_runtime.h>
#include <cstdint>
#include <cstddef>

#define KNB 20
#define NPTS 8192
#define BATCH 2
#define TOTAL (BATCH * NPTS)

// ---------------------------------------------------------------------------
// K0: transpose pts to SoA for coalesced, L1-hot KNN candidate reads.
// ---------------------------------------------------------------------------
__global__ __launch_bounds__(256) void k_pose(const float* __restrict__ pts,
                                              float* __restrict__ ptsT) {
  int gid = blockIdx.x * 256 + threadIdx.x;
  if (gid >= TOTAL * 3) return;
  int pt = gid / 3, d = gid % 3;
  int b = pt >> 13, p = pt & (NPTS - 1);
  ptsT[((size_t)b * 3 + d) * NPTS + p] = pts[gid];
}

// ---------------------------------------------------------------------------
// K1: pointwise conv 3->64 + relu
// ---------------------------------------------------------------------------
__global__ __launch_bounds__(256) void k_conv(const float* __restrict__ pts,
                                              const float* __restrict__ w,
                                              const float* __restrict__ b,
                                              float* __restrict__ x0) {
  int gid = blockIdx.x * 256 + threadIdx.x;
  if (gid >= TOTAL * 64) return;
  int p = gid >> 6, c = gid & 63;
  float px = pts[p * 3 + 0], py = pts[p * 3 + 1], pz = pts[p * 3 + 2];
  float acc = b[c] + px * w[c] + py * w[64 + c] + pz * w[128 + c];
  x0[gid] = fmaxf(acc, 0.f);
}

// ---------------------------------------------------------------------------
// K2: KNN v4 — barrier-free, no LDS, CHEAP tau.
// R14's per-chunk bitonic sort (42 serially-dependent ds_bpermute ops —
// __shfl compiles to the LDS pipe, ~120cyc latency) was the stall: VALU 54%.
// Replaced by tau = wave-MIN of dist[19] (6 shfl+min). VALIDITY: the global
// 20th-best <= every lane's local 20th (each lane's 20 elements are all <=
// its dist[19]), so min_L dist_L[19] >= global 20th >= final 20th -> skipping
// d2 > tau is exact; d2 <= tau still takes the exact insert path, and ties
// (d2 == tau) are never skipped.
// d2 via __fmul_rn/__fadd_rn: bit-identical to numpy's ((dx²+dy²)+dz²).
// ---------------------------------------------------------------------------
__global__ __launch_bounds__(256) void k_knn(const float* __restrict__ ptsT,
                                             const float* __restrict__ pts,
                                             int* __restrict__ idxbuf) {
  int tid = threadIdx.x;
  int wv = tid >> 6, lane = tid & 63;
  int q = blockIdx.x * 4 + wv;            // 4 independent waves per block
  int bq = q >> 13;
  const float* px = ptsT + (size_t)bq * 3 * NPTS;
  const float* py = px + NPTS;
  const float* pz = py + NPTS;
  float qx = pts[q * 3 + 0], qy = pts[q * 3 + 1], qz = pts[q * 3 + 2];

  float dist[KNB];
  int id[KNB];
#pragma unroll
  for (int j = 0; j < KNB; j++) { dist[j] = 3.402823466e38f; id[j] = 0; }
  float tau = 3.402823466e38f;

  for (int chunk = 0; chunk < 8; chunk++) {
    if (chunk) {
      // tau = wave-min of per-lane 20th-best (valid exact skip bound).
      float t = dist[KNB - 1];
#pragma unroll
      for (int off = 32; off >= 1; off >>= 1)
        t = fminf(t, __shfl_xor(t, off));
      tau = t;
    }

    int base = chunk * 1024;
#pragma unroll 4
    for (int i = 0; i < 16; i++) {
      int c = base + lane + (i << 6);
      float dx = qx - px[c];
      float dy = qy - py[c];
      float dz = qz - pz[c];
      float d2 = __fadd_rn(__fadd_rn(__fmul_rn(dx, dx), __fmul_rn(dy, dy)),
                           __fmul_rn(dz, dz));
      if (d2 <= tau && d2 < dist[KNB - 1]) {
        int cid = c;
        // branchless sorted insert (ascending); strict < keeps lax.top_k
        // stable tie-breaking within a lane.
#pragma unroll
        for (int j = KNB - 1; j >= 0; j--) {
          bool cj = d2 < dist[j];
          bool cjm1 = (j > 0) && (d2 < dist[j - 1]);
          if (cj) {
            dist[j] = cjm1 ? dist[j - 1] : d2;
            id[j]   = cjm1 ? id[j - 1]   : cid;
          }
        }
      }
    }
  }

  // 20-step cross-lane merge: min over packed (d2bits, cid) — exact
  // lax.top_k order (d2 asc, index asc).
  int bqoff = bq * NPTS;
  for (int step = 0; step < KNB; step++) {
    unsigned long long p =
        ((unsigned long long)__float_as_uint(dist[0]) << 32) | (unsigned)id[0];
    unsigned long long m = p;
#pragma unroll
    for (int off = 32; off >= 1; off >>= 1) {
      unsigned long long o = __shfl_xor(m, off);
      m = (o < m) ? o : m;
    }
    if (lane == 0) idxbuf[q * KNB + step] = bqoff + (int)(m & 0xffffffffULL);
    if (p == m) {
#pragma unroll
      for (int j = 0; j < KNB - 1; j++) { dist[j] = dist[j + 1]; id[j] = id[j + 1]; }
      dist[KNB - 1] = 3.402823466e38f;
    }
  }
}

// ---------------------------------------------------------------------------
// K3: qkv GEMM (TOTAL,64) @ (64,192) — float4 outputs per thread.
// ---------------------------------------------------------------------------
__global__ __launch_bounds__(256) void k_qkv(const float* __restrict__ x,
                                             const float* __restrict__ w,
                                             float* __restrict__ qkv) {
  int gid = blockIdx.x * 256 + threadIdx.x;
  if (gid >= TOTAL * 48) return;
  int p = gid / 48, c4 = (gid % 48) * 4;
  const float* xr = x + (size_t)p * 64;
  float4 a = make_float4(0.f, 0.f, 0.f, 0.f);
#pragma unroll 8
  for (int k = 0; k < 64; k++) {
    float xv = xr[k];
    float4 wv = *(const float4*)&w[k * 192 + c4];
    a.x += xv * wv.x; a.y += xv * wv.y; a.z += xv * wv.z; a.w += xv * wv.w;
  }
  *(float4*)&qkv[(size_t)p * 192 + c4] = a;
}

// ---------------------------------------------------------------------------
// K3b: kh[g][c] = K_g . aw1_top[:,c]; shared by all queries referencing g.
// ---------------------------------------------------------------------------
__global__ __launch_bounds__(256) void k_hh(const float* __restrict__ qkv,
                                            const float* __restrict__ aw1,
                                            float* __restrict__ kh) {
  int gid = blockIdx.x * 256 + threadIdx.x;   // TOTAL*64 threads
  int g = gid >> 6, c4 = (gid & 63) * 4;
  const float* kr = qkv + (size_t)g * 192 + 64;
  float4 a = make_float4(0.f, 0.f, 0.f, 0.f);
#pragma unroll 8
  for (int k = 0; k < 64; k++) {
    float kv = kr[k];
    float4 wv = *(const float4*)&aw1[(size_t)k * 256 + c4];
    a.x += kv * wv.x; a.y += kv * wv.y; a.z += kv * wv.z; a.w += kv * wv.w;
  }
  *(float4*)&kh[(size_t)g * 256 + c4] = a;
}

// ---------------------------------------------------------------------------
// K4: wave-per-query fused attention, VGPR-minimized for occupancy:
//  - phase B: 4 NON-UNROLLED passes of 5 neighbors (acc[5][4] = 20 regs);
//    sims stored to LDS (s_sim) so no dynamically-indexed register array
//    (R4 scratch trap). aw1_bot re-streamed per pass (L1/L2-hot).
//  - hidden = qh - kh[g] + rpe@aw1_bot (kh precomputed; qh via readlane).
//  - A2 via readlane; streaming softmax (exp recomputed, bit-identical).
//  Block-uniform barriers only (R9/R10 zero-barrier = container death).
//  No min-waves launch-bounds arg (R5 trap).
// ---------------------------------------------------------------------------
__global__ __launch_bounds__(256) void k_attn(
    const float* __restrict__ pos, const float* __restrict__ qkv,
    const int* __restrict__ idxbuf, const float* __restrict__ kh,
    const float* __restrict__ pw1, const float* __restrict__ pb1,
    const float* __restrict__ pw2, const float* __restrict__ pb2,
    const float* __restrict__ aw1, const float* __restrict__ ab1,
    const float* __restrict__ aw2, const float* __restrict__ ab2,
    float* __restrict__ xout) {
  __shared__ float s_rpe[4][KNB][64];   // 20 KB: [wave][n][c]
  __shared__ float s_sim[4][KNB];
  __shared__ int   s_nb[4][24];

  int tid = threadIdx.x;
  int wv = tid >> 6, lane = tid & 63;
  int i = blockIdx.x * 4 + wv;

  if (lane < KNB) s_nb[wv][lane] = idxbuf[i * KNB + lane];
  float qv = qkv[(size_t)i * 192 + lane];    // q row, distributed by lane
  float px = pos[i * 3 + 0], py = pos[i * 3 + 1], pz = pos[i * 3 + 2];
  __syncthreads();

#define RL(x, l) __uint_as_float(__builtin_amdgcn_readlane(__float_as_uint(x), (l)))
  // A1+A2: t1 in registers (channel=lane), rpe via readlane broadcast.
  {
    float t1[KNB];
    float w1x = pw1[lane], w1y = pw1[64 + lane], w1z = pw1[128 + lane];
    float b1h = pb1[lane];
#pragma unroll
    for (int n = 0; n < KNB; n++) {
      int g = s_nb[wv][n];
      float rx = px - pos[g * 3 + 0];
      float ry = py - pos[g * 3 + 1];
      float rz = pz - pos[g * 3 + 2];
      t1[n] = fmaxf(b1h + rx * w1x + ry * w1y + rz * w1z, 0.f);
    }
    float racc[KNB];
    float b2c = pb2[lane];
#pragma unroll
    for (int n = 0; n < KNB; n++) racc[n] = b2c;
#pragma unroll
    for (int h8 = 0; h8 < 64; h8 += 8) {
      float w0 = pw2[(h8 + 0) * 64 + lane];
      float w1 = pw2[(h8 + 1) * 64 + lane];
      float w2 = pw2[(h8 + 2) * 64 + lane];
      float w3 = pw2[(h8 + 3) * 64 + lane];
      float w4 = pw2[(h8 + 4) * 64 + lane];
      float w5 = pw2[(h8 + 5) * 64 + lane];
      float w6 = pw2[(h8 + 6) * 64 + lane];
      float w7 = pw2[(h8 + 7) * 64 + lane];
#pragma unroll
      for (int n = 0; n < KNB; n++) {
        racc[n] += RL(t1[n], h8 + 0) * w0 + RL(t1[n], h8 + 1) * w1 +
                   RL(t1[n], h8 + 2) * w2 + RL(t1[n], h8 + 3) * w3 +
                   RL(t1[n], h8 + 4) * w4 + RL(t1[n], h8 + 5) * w5 +
                   RL(t1[n], h8 + 6) * w6 + RL(t1[n], h8 + 7) * w7;
      }
    }
#pragma unroll
    for (int n = 0; n < KNB; n++) s_rpe[wv][n][lane] = racc[n];
  }
  __syncthreads();

  // qh (once per query): q . aw1_top[:,col], lane owns cols 4*lane..+3
  int col0 = lane * 4;
  float4 qh4 = make_float4(0.f, 0.f, 0.f, 0.f);
#pragma unroll 8
  for (int k = 0; k < 64; k++) {
    float qk = RL(qv, k);
    float4 w = *(const float4*)&aw1[(size_t)k * 256 + col0];
    qh4.x += qk * w.x; qh4.y += qk * w.y; qh4.z += qk * w.z; qh4.w += qk * w.w;
  }
#undef RL

  // B: 4 sequential passes of 5 neighbors; sims -> LDS.
  float4 b1v = *(const float4*)&ab1[col0];
  float4 w2v = *(const float4*)&aw2[col0];
  float ab2v = ab2[0];
#pragma unroll 1
  for (int pass = 0; pass < 4; pass++) {
    int nb0 = pass * 5;
    float acc[5][4];
#pragma unroll
    for (int n = 0; n < 5; n++) {
      int g = s_nb[wv][nb0 + n];
      float4 kv = *(const float4*)&kh[(size_t)g * 256 + col0];
      acc[n][0] = qh4.x - kv.x; acc[n][1] = qh4.y - kv.y;
      acc[n][2] = qh4.z - kv.z; acc[n][3] = qh4.w - kv.w;
    }
#pragma unroll 2
    for (int kc = 0; kc < 64; kc += 4) {
      float4 w0 = *(const float4*)&aw1[(size_t)(64 + kc + 0) * 256 + col0];
      float4 w1 = *(const float4*)&aw1[(size_t)(64 + kc + 1) * 256 + col0];
      float4 w2 = *(const float4*)&aw1[(size_t)(64 + kc + 2) * 256 + col0];
      float4 w3 = *(const float4*)&aw1[(size_t)(64 + kc + 3) * 256 + col0];
#pragma unroll
      for (int n = 0; n < 5; n++) {
        float4 iv = *(float4*)&s_rpe[wv][nb0 + n][kc];
        acc[n][0] += iv.x * w0.x + iv.y * w1.x + iv.z * w2.x + iv.w * w3.x;
        acc[n][1] += iv.x * w0.y + iv.y * w1.y + iv.z * w2.y + iv.w * w3.y;
        acc[n][2] += iv.x * w0.z + iv.y * w1.z + iv.z * w2.z + iv.w * w3.z;
        acc[n][3] += iv.x * w0.w + iv.y * w1.w + iv.z * w2.w + iv.w * w3.w;
      }
    }
#pragma unroll
    for (int n = 0; n < 5; n++) {
      float s = fmaxf(acc[n][0] + b1v.x, 0.f) * w2v.x +
                fmaxf(acc[n][1] + b1v.y, 0.f) * w2v.y +
                fmaxf(acc[n][2] + b1v.z, 0.f) * w2v.z +
                fmaxf(acc[n][3] + b1v.w, 0.f) * w2v.w;
#pragma unroll
      for (int off = 32; off >= 1; off >>= 1) s += __shfl_xor(s, off);
      if (lane == 0) s_sim[wv][nb0 + n] = s + ab2v;
    }
  }
  __syncthreads();

  // C: streaming softmax from LDS sims (exp recomputed; bit-identical)
  float mx = -3.402823466e38f;
#pragma unroll
  for (int n = 0; n < KNB; n++) mx = fmaxf(mx, s_sim[wv][n]);
  float sum = 0.f;
#pragma unroll
  for (int n = 0; n < KNB; n++) sum += expf(s_sim[wv][n] - mx);
  float inv = 1.f / sum;
  float o = 0.f;
#pragma unroll
  for (int n = 0; n < KNB; n++) {
    int g = s_nb[wv][n];
    float vnb = qkv[(size_t)g * 192 + 128 + lane] + s_rpe[wv][n][lane];
    o += (expf(s_sim[wv][n] - mx) * inv) * vnb;
  }
  xout[(size_t)i * 64 + lane] = o;
}

// ---------------------------------------------------------------------------
// K5: global max-pool + fc1 + fc3 (unchanged)
// ---------------------------------------------------------------------------
__global__ __launch_bounds__(256) void k_final(const float* __restrict__ x,
                                               const float* __restrict__ fc1w,
                                               const float* __restrict__ fc1b,
                                               const float* __restrict__ fc3w,
                                               const float* __restrict__ fc3b,
                                               float* __restrict__ out) {
  __shared__ float red[4][64];
  __shared__ float m[64];
  __shared__ float h1[32];
  int b = blockIdx.x;
  int tid = threadIdx.x;
  int c = tid & 63, pg = tid >> 6;
  float mx = -3.402823466e38f;
  for (int p = pg; p < NPTS; p += 4)
    mx = fmaxf(mx, x[((size_t)b * NPTS + p) * 64 + c]);
  red[pg][c] = mx;
  __syncthreads();
  if (tid < 64)
    m[c] = fmaxf(fmaxf(red[0][c], red[1][c]), fmaxf(red[2][c], red[3][c]));
  __syncthreads();
  if (tid < 32) {
    float a = fc1b[tid];
#pragma unroll 8
    for (int k = 0; k < 64; k++) a += m[k] * fc1w[k * 32 + tid];
    h1[tid] = fmaxf(a, 0.f);
  }
  __syncthreads();
  if (tid < 3) {
    float a = fc3b[tid];
#pragma unroll
    for (int k = 0; k < 32; k++) a += h1[k] * fc3w[k * 3 + tid];
    out[b * 3 + tid] = a;
  }
}

// ---------------------------------------------------------------------------
// Workspace (peak 36.2 MB):
//   idx  @ 0       (1.31 MB) | ptsT @ 1.5 MB (0.2 MB)
//   qkv  @ 2 MB    (12.6 MB) | kh @ 15 MB (16.8 MB)
//   act  @ 32 MB   (4.2 MB)  x0/x1/x2 share one slot
// ---------------------------------------------------------------------------
extern "C" void kernel_launch(void* const* d_in, const int* in_sizes, int n_in,
                              void* d_out, int out_size, void* d_ws,
                              size_t ws_size, hipStream_t stream) {
  const float* pts    = (const float*)d_in[0];
  const float* conv_w = (const float*)d_in[1];
  const float* conv_b = (const float*)d_in[2];
  const float* fc1w = (const float*)d_in[21];
  const float* fc1b = (const float*)d_in[22];
  const float* fc3w = (const float*)d_in[23];
  const float* fc3b = (const float*)d_in[24];
  float* outp = (float*)d_out;

  char* ws = (char*)d_ws;
  int*   idx  = (int*)  (ws);
  float* ptsT = (float*)(ws + (size_t)1536 * 1024);
  float* qkv  = (float*)(ws + (size_t)2 * 1048576);
  float* kh   = (float*)(ws + (size_t)15 * 1048576);
  float* act  = (float*)(ws + (size_t)32 * 1048576);

  k_pose<<<(TOTAL * 3 + 255) / 256, 256, 0, stream>>>(pts, ptsT);
  k_conv<<<(TOTAL * 64 + 255) / 256, 256, 0, stream>>>(pts, conv_w, conv_b, act);
  k_knn<<<TOTAL / 4, 256, 0, stream>>>(ptsT, pts, idx);

  for (int layer = 0; layer < 2; layer++) {
    int base = 3 + layer * 9;
    const float* qkvw = (const float*)d_in[base + 0];
    const float* aw1  = (const float*)d_in[base + 5];
    k_qkv<<<(TOTAL * 48 + 255) / 256, 256, 0, stream>>>(act, qkvw, qkv);
    k_hh<<<(TOTAL * 64 + 255) / 256, 256, 0, stream>>>(qkv, aw1, kh);
    k_attn<<<TOTAL / 4, 256, 0, stream>>>(
        pts, qkv, idx, kh,
        (const float*)d_in[base + 1], (const float*)d_in[base + 2],
        (const float*)d_in[base + 3], (const float*)d_in[base + 4],
        aw1, (const float*)d_in[base + 6],
        (const float*)d_in[base + 7], (const float*)d_in[base + 8],
        act);
  }
  k_final<<<BATCH, 256, 0, stream>>>(act, fc1w, fc1b, fc3w, fc3b, outp);
}

// Round 16
// 1515.518 us; speedup vs baseline: 1.1332x; 1.1332x over previous
//
#include <hip/hip_runtime.h>
#include <cstdint>
#include <cstddef>

#define KNB 20
#define NPTS 8192
#define BATCH 2
#define TOTAL (BATCH * NPTS)

// ---------------------------------------------------------------------------
// K0: transpose pts to SoA for coalesced, L1-hot KNN candidate reads.
// ---------------------------------------------------------------------------
__global__ __launch_bounds__(256) void k_pose(const float* __restrict__ pts,
                                              float* __restrict__ ptsT) {
  int gid = blockIdx.x * 256 + threadIdx.x;
  if (gid >= TOTAL * 3) return;
  int pt = gid / 3, d = gid % 3;
  int b = pt >> 13, p = pt & (NPTS - 1);
  ptsT[((size_t)b * 3 + d) * NPTS + p] = pts[gid];
}

// ---------------------------------------------------------------------------
// K1: pointwise conv 3->64 + relu
// ---------------------------------------------------------------------------
__global__ __launch_bounds__(256) void k_conv(const float* __restrict__ pts,
                                              const float* __restrict__ w,
                                              const float* __restrict__ b,
                                              float* __restrict__ x0) {
  int gid = blockIdx.x * 256 + threadIdx.x;
  if (gid >= TOTAL * 64) return;
  int p = gid >> 6, c = gid & 63;
  float px = pts[p * 3 + 0], py = pts[p * 3 + 1], pz = pts[p * 3 + 2];
  float acc = b[c] + px * w[c] + py * w[64 + c] + pz * w[128 + c];
  x0[gid] = fmaxf(acc, 0.f);
}

// ---------------------------------------------------------------------------
// K2: KNN v5 — barrier-free, no LDS, TIGHT tau at HALF the shfl cost.
// R15 lesson: tau = wave-min(dist[19]) is valid but LOOSE early (infinite
// until a lane holds 20 candidates) -> insert work ballooned (641 µs, VALU
// 59%). R14's tau (20th-smallest lane-head) is tight but cost 42 dependent
// 64-bit shfl stages. Here: bitonic sort of the 64 HEAD VALUES as plain f32
// (21 stages) — the head-value multiset is identical to R14's packed sort,
// so sorted[19] == R14's tau EXACTLY; skipping d2 > tau is exact (the 20
// smallest heads are 20 real candidates on distinct lanes).
// d2 via __fmul_rn/__fadd_rn: bit-identical to numpy's ((dx²+dy²)+dz²).
// ---------------------------------------------------------------------------
__global__ __launch_bounds__(256) void k_knn(const float* __restrict__ ptsT,
                                             const float* __restrict__ pts,
                                             int* __restrict__ idxbuf) {
  int tid = threadIdx.x;
  int wv = tid >> 6, lane = tid & 63;
  int q = blockIdx.x * 4 + wv;            // 4 independent waves per block
  int bq = q >> 13;
  const float* px = ptsT + (size_t)bq * 3 * NPTS;
  const float* py = px + NPTS;
  const float* pz = py + NPTS;
  float qx = pts[q * 3 + 0], qy = pts[q * 3 + 1], qz = pts[q * 3 + 2];

  float dist[KNB];
  int id[KNB];
#pragma unroll
  for (int j = 0; j < KNB; j++) { dist[j] = 3.402823466e38f; id[j] = 0; }
  float tau = 3.402823466e38f;

  for (int chunk = 0; chunk < 8; chunk++) {
    if (chunk) {
      // tau = 20th smallest of the 64 lane-head d2 values (f32 bitonic).
      float h = dist[0];
#pragma unroll
      for (int k = 2; k <= 64; k <<= 1) {
#pragma unroll
        for (int j = k >> 1; j > 0; j >>= 1) {
          float o = __shfl_xor(h, j);
          bool up = ((lane & k) == 0);
          bool lower = ((lane & j) == 0);
          bool takeMin = (up == lower);
          bool lt = h < o;
          h = (takeMin == lt) ? h : o;
        }
      }
      tau = __shfl(h, 19);
    }

    int base = chunk * 1024;
#pragma unroll 4
    for (int i = 0; i < 16; i++) {
      int c = base + lane + (i << 6);
      float dx = qx - px[c];
      float dy = qy - py[c];
      float dz = qz - pz[c];
      float d2 = __fadd_rn(__fadd_rn(__fmul_rn(dx, dx), __fmul_rn(dy, dy)),
                           __fmul_rn(dz, dz));
      if (d2 <= tau && d2 < dist[KNB - 1]) {
        int cid = c;
        // branchless sorted insert (ascending); strict < keeps lax.top_k
        // stable tie-breaking within a lane.
#pragma unroll
        for (int j = KNB - 1; j >= 0; j--) {
          bool cj = d2 < dist[j];
          bool cjm1 = (j > 0) && (d2 < dist[j - 1]);
          if (cj) {
            dist[j] = cjm1 ? dist[j - 1] : d2;
            id[j]   = cjm1 ? id[j - 1]   : cid;
          }
        }
      }
    }
  }

  // 20-step cross-lane merge: min over packed (d2bits, cid) — exact
  // lax.top_k order (d2 asc, index asc).
  int bqoff = bq * NPTS;
  for (int step = 0; step < KNB; step++) {
    unsigned long long p =
        ((unsigned long long)__float_as_uint(dist[0]) << 32) | (unsigned)id[0];
    unsigned long long m = p;
#pragma unroll
    for (int off = 32; off >= 1; off >>= 1) {
      unsigned long long o = __shfl_xor(m, off);
      m = (o < m) ? o : m;
    }
    if (lane == 0) idxbuf[q * KNB + step] = bqoff + (int)(m & 0xffffffffULL);
    if (p == m) {
#pragma unroll
      for (int j = 0; j < KNB - 1; j++) { dist[j] = dist[j + 1]; id[j] = id[j + 1]; }
      dist[KNB - 1] = 3.402823466e38f;
    }
  }
}

// ---------------------------------------------------------------------------
// K3: FUSED qkv + kh (wave per point). Lane computes q[lane], k[lane],
// v[lane] (three 64-dot products); writes q and v (k is consumed ONLY by
// kh — never materialized to global); kh[p][4*lane..+3] = k . aw1_top via
// readlane broadcast of the register-resident k row. Replaces the separate
// k_qkv + k_hh launches (one less launch + no k round-trip per layer).
// ---------------------------------------------------------------------------
__global__ __launch_bounds__(256) void k_pre(const float* __restrict__ x,
                                             const float* __restrict__ w,
                                             const float* __restrict__ aw1,
                                             float* __restrict__ qkv,
                                             float* __restrict__ kh) {
  int tid = threadIdx.x;
  int wv = tid >> 6, lane = tid & 63;
  int p = blockIdx.x * 4 + wv;
  const float* xr = x + (size_t)p * 64;

  float qa = 0.f, ka = 0.f, va = 0.f;
#pragma unroll 8
  for (int h = 0; h < 64; h++) {
    float xv = xr[h];
    qa += xv * w[h * 192 + lane];
    ka += xv * w[h * 192 + 64 + lane];
    va += xv * w[h * 192 + 128 + lane];
  }
  qkv[(size_t)p * 192 + lane] = qa;
  qkv[(size_t)p * 192 + 128 + lane] = va;

#define RL(x_, l_) __uint_as_float(__builtin_amdgcn_readlane(__float_as_uint(x_), (l_)))
  int c4 = lane * 4;
  float4 a = make_float4(0.f, 0.f, 0.f, 0.f);
#pragma unroll 8
  for (int h = 0; h < 64; h++) {
    float kb = RL(ka, h);
    float4 wv4 = *(const float4*)&aw1[(size_t)h * 256 + c4];
    a.x += kb * wv4.x; a.y += kb * wv4.y; a.z += kb * wv4.z; a.w += kb * wv4.w;
  }
#undef RL
  *(float4*)&kh[(size_t)p * 256 + c4] = a;
}

// ---------------------------------------------------------------------------
// K4: wave-per-query fused attention (unchanged from R15 — best attn yet):
//  4 non-unrolled passes of 5 neighbors (acc[5][4]); sims -> LDS;
//  hidden = qh - kh[g] + rpe@aw1_bot; A2 via readlane; streaming softmax.
//  Block-uniform barriers only (R9/R10 zero-barrier = container death).
//  No min-waves launch-bounds arg (R5 trap); no dyn-indexed reg arrays (R4).
// ---------------------------------------------------------------------------
__global__ __launch_bounds__(256) void k_attn(
    const float* __restrict__ pos, const float* __restrict__ qkv,
    const int* __restrict__ idxbuf, const float* __restrict__ kh,
    const float* __restrict__ pw1, const float* __restrict__ pb1,
    const float* __restrict__ pw2, const float* __restrict__ pb2,
    const float* __restrict__ aw1, const float* __restrict__ ab1,
    const float* __restrict__ aw2, const float* __restrict__ ab2,
    float* __restrict__ xout) {
  __shared__ float s_rpe[4][KNB][64];   // 20 KB: [wave][n][c]
  __shared__ float s_sim[4][KNB];
  __shared__ int   s_nb[4][24];

  int tid = threadIdx.x;
  int wv = tid >> 6, lane = tid & 63;
  int i = blockIdx.x * 4 + wv;

  if (lane < KNB) s_nb[wv][lane] = idxbuf[i * KNB + lane];
  float qv = qkv[(size_t)i * 192 + lane];    // q row, distributed by lane
  float px = pos[i * 3 + 0], py = pos[i * 3 + 1], pz = pos[i * 3 + 2];
  __syncthreads();

#define RL(x, l) __uint_as_float(__builtin_amdgcn_readlane(__float_as_uint(x), (l)))
  // A1+A2: t1 in registers (channel=lane), rpe via readlane broadcast.
  {
    float t1[KNB];
    float w1x = pw1[lane], w1y = pw1[64 + lane], w1z = pw1[128 + lane];
    float b1h = pb1[lane];
#pragma unroll
    for (int n = 0; n < KNB; n++) {
      int g = s_nb[wv][n];
      float rx = px - pos[g * 3 + 0];
      float ry = py - pos[g * 3 + 1];
      float rz = pz - pos[g * 3 + 2];
      t1[n] = fmaxf(b1h + rx * w1x + ry * w1y + rz * w1z, 0.f);
    }
    float racc[KNB];
    float b2c = pb2[lane];
#pragma unroll
    for (int n = 0; n < KNB; n++) racc[n] = b2c;
#pragma unroll
    for (int h8 = 0; h8 < 64; h8 += 8) {
      float w0 = pw2[(h8 + 0) * 64 + lane];
      float w1 = pw2[(h8 + 1) * 64 + lane];
      float w2 = pw2[(h8 + 2) * 64 + lane];
      float w3 = pw2[(h8 + 3) * 64 + lane];
      float w4 = pw2[(h8 + 4) * 64 + lane];
      float w5 = pw2[(h8 + 5) * 64 + lane];
      float w6 = pw2[(h8 + 6) * 64 + lane];
      float w7 = pw2[(h8 + 7) * 64 + lane];
#pragma unroll
      for (int n = 0; n < KNB; n++) {
        racc[n] += RL(t1[n], h8 + 0) * w0 + RL(t1[n], h8 + 1) * w1 +
                   RL(t1[n], h8 + 2) * w2 + RL(t1[n], h8 + 3) * w3 +
                   RL(t1[n], h8 + 4) * w4 + RL(t1[n], h8 + 5) * w5 +
                   RL(t1[n], h8 + 6) * w6 + RL(t1[n], h8 + 7) * w7;
      }
    }
#pragma unroll
    for (int n = 0; n < KNB; n++) s_rpe[wv][n][lane] = racc[n];
  }
  __syncthreads();

  // qh (once per query): q . aw1_top[:,col], lane owns cols 4*lane..+3
  int col0 = lane * 4;
  float4 qh4 = make_float4(0.f, 0.f, 0.f, 0.f);
#pragma unroll 8
  for (int k = 0; k < 64; k++) {
    float qk = RL(qv, k);
    float4 w = *(const float4*)&aw1[(size_t)k * 256 + col0];
    qh4.x += qk * w.x; qh4.y += qk * w.y; qh4.z += qk * w.z; qh4.w += qk * w.w;
  }
#undef RL

  // B: 4 sequential passes of 5 neighbors; sims -> LDS.
  float4 b1v = *(const float4*)&ab1[col0];
  float4 w2v = *(const float4*)&aw2[col0];
  float ab2v = ab2[0];
#pragma unroll 1
  for (int pass = 0; pass < 4; pass++) {
    int nb0 = pass * 5;
    float acc[5][4];
#pragma unroll
    for (int n = 0; n < 5; n++) {
      int g = s_nb[wv][nb0 + n];
      float4 kv = *(const float4*)&kh[(size_t)g * 256 + col0];
      acc[n][0] = qh4.x - kv.x; acc[n][1] = qh4.y - kv.y;
      acc[n][2] = qh4.z - kv.z; acc[n][3] = qh4.w - kv.w;
    }
#pragma unroll 2
    for (int kc = 0; kc < 64; kc += 4) {
      float4 w0 = *(const float4*)&aw1[(size_t)(64 + kc + 0) * 256 + col0];
      float4 w1 = *(const float4*)&aw1[(size_t)(64 + kc + 1) * 256 + col0];
      float4 w2 = *(const float4*)&aw1[(size_t)(64 + kc + 2) * 256 + col0];
      float4 w3 = *(const float4*)&aw1[(size_t)(64 + kc + 3) * 256 + col0];
#pragma unroll
      for (int n = 0; n < 5; n++) {
        float4 iv = *(float4*)&s_rpe[wv][nb0 + n][kc];
        acc[n][0] += iv.x * w0.x + iv.y * w1.x + iv.z * w2.x + iv.w * w3.x;
        acc[n][1] += iv.x * w0.y + iv.y * w1.y + iv.z * w2.y + iv.w * w3.y;
        acc[n][2] += iv.x * w0.z + iv.y * w1.z + iv.z * w2.z + iv.w * w3.z;
        acc[n][3] += iv.x * w0.w + iv.y * w1.w + iv.z * w2.w + iv.w * w3.w;
      }
    }
#pragma unroll
    for (int n = 0; n < 5; n++) {
      float s = fmaxf(acc[n][0] + b1v.x, 0.f) * w2v.x +
                fmaxf(acc[n][1] + b1v.y, 0.f) * w2v.y +
                fmaxf(acc[n][2] + b1v.z, 0.f) * w2v.z +
                fmaxf(acc[n][3] + b1v.w, 0.f) * w2v.w;
#pragma unroll
      for (int off = 32; off >= 1; off >>= 1) s += __shfl_xor(s, off);
      if (lane == 0) s_sim[wv][nb0 + n] = s + ab2v;
    }
  }
  __syncthreads();

  // C: streaming softmax from LDS sims (exp recomputed; bit-identical)
  float mx = -3.402823466e38f;
#pragma unroll
  for (int n = 0; n < KNB; n++) mx = fmaxf(mx, s_sim[wv][n]);
  float sum = 0.f;
#pragma unroll
  for (int n = 0; n < KNB; n++) sum += expf(s_sim[wv][n] - mx);
  float inv = 1.f / sum;
  float o = 0.f;
#pragma unroll
  for (int n = 0; n < KNB; n++) {
    int g = s_nb[wv][n];
    float vnb = qkv[(size_t)g * 192 + 128 + lane] + s_rpe[wv][n][lane];
    o += (expf(s_sim[wv][n] - mx) * inv) * vnb;
  }
  xout[(size_t)i * 64 + lane] = o;
}

// ---------------------------------------------------------------------------
// K5: global max-pool + fc1 + fc3 (unchanged)
// ---------------------------------------------------------------------------
__global__ __launch_bounds__(256) void k_final(const float* __restrict__ x,
                                               const float* __restrict__ fc1w,
                                               const float* __restrict__ fc1b,
                                               const float* __restrict__ fc3w,
                                               const float* __restrict__ fc3b,
                                               float* __restrict__ out) {
  __shared__ float red[4][64];
  __shared__ float m[64];
  __shared__ float h1[32];
  int b = blockIdx.x;
  int tid = threadIdx.x;
  int c = tid & 63, pg = tid >> 6;
  float mx = -3.402823466e38f;
  for (int p = pg; p < NPTS; p += 4)
    mx = fmaxf(mx, x[((size_t)b * NPTS + p) * 64 + c]);
  red[pg][c] = mx;
  __syncthreads();
  if (tid < 64)
    m[c] = fmaxf(fmaxf(red[0][c], red[1][c]), fmaxf(red[2][c], red[3][c]));
  __syncthreads();
  if (tid < 32) {
    float a = fc1b[tid];
#pragma unroll 8
    for (int k = 0; k < 64; k++) a += m[k] * fc1w[k * 32 + tid];
    h1[tid] = fmaxf(a, 0.f);
  }
  __syncthreads();
  if (tid < 3) {
    float a = fc3b[tid];
#pragma unroll
    for (int k = 0; k < 32; k++) a += h1[k] * fc3w[k * 3 + tid];
    out[b * 3 + tid] = a;
  }
}

// ---------------------------------------------------------------------------
// Workspace (peak 36.2 MB):
//   idx  @ 0       (1.31 MB) | ptsT @ 1.5 MB (0.2 MB)
//   qkv  @ 2 MB    (12.6 MB) | kh @ 15 MB (16.8 MB)
//   act  @ 32 MB   (4.2 MB)  x0/x1/x2 share one slot
// ---------------------------------------------------------------------------
extern "C" void kernel_launch(void* const* d_in, const int* in_sizes, int n_in,
                              void* d_out, int out_size, void* d_ws,
                              size_t ws_size, hipStream_t stream) {
  const float* pts    = (const float*)d_in[0];
  const float* conv_w = (const float*)d_in[1];
  const float* conv_b = (const float*)d_in[2];
  const float* fc1w = (const float*)d_in[21];
  const float* fc1b = (const float*)d_in[22];
  const float* fc3w = (const float*)d_in[23];
  const float* fc3b = (const float*)d_in[24];
  float* outp = (float*)d_out;

  char* ws = (char*)d_ws;
  int*   idx  = (int*)  (ws);
  float* ptsT = (float*)(ws + (size_t)1536 * 1024);
  float* qkv  = (float*)(ws + (size_t)2 * 1048576);
  float* kh   = (float*)(ws + (size_t)15 * 1048576);
  float* act  = (float*)(ws + (size_t)32 * 1048576);

  k_pose<<<(TOTAL * 3 + 255) / 256, 256, 0, stream>>>(pts, ptsT);
  k_conv<<<(TOTAL * 64 + 255) / 256, 256, 0, stream>>>(pts, conv_w, conv_b, act);
  k_knn<<<TOTAL / 4, 256, 0, stream>>>(ptsT, pts, idx);

  for (int layer = 0; layer < 2; layer++) {
    int base = 3 + layer * 9;
    const float* qkvw = (const float*)d_in[base + 0];
    const float* aw1  = (const float*)d_in[base + 5];
    k_pre<<<TOTAL / 4, 256, 0, stream>>>(act, qkvw, aw1, qkv, kh);
    k_attn<<<TOTAL / 4, 256, 0, stream>>>(
        pts, qkv, idx, kh,
        (const float*)d_in[base + 1], (const float*)d_in[base + 2],
        (const float*)d_in[base + 3], (const float*)d_in[base + 4],
        aw1, (const float*)d_in[base + 6],
        (const float*)d_in[base + 7], (const float*)d_in[base + 8],
        act);
  }
  k_final<<<BATCH, 256, 0, stream>>>(act, fc1w, fc1b, fc3w, fc3b, outp);
}

// Round 18
// 1454.198 us; speedup vs baseline: 1.1809x; 1.0422x over previous
//
#include <hip/hip_runtime.h>
#include <cstdint>
#include <cstddef>

#define KNB 20
#define NPTS 8192
#define BATCH 2
#define TOTAL (BATCH * NPTS)

// ---------------------------------------------------------------------------
// K0: transpose pts to SoA for coalesced, L1-hot KNN candidate reads.
// ---------------------------------------------------------------------------
__global__ __launch_bounds__(256) void k_pose(const float* __restrict__ pts,
                                              float* __restrict__ ptsT) {
  int gid = blockIdx.x * 256 + threadIdx.x;
  if (gid >= TOTAL * 3) return;
  int pt = gid / 3, d = gid % 3;
  int b = pt >> 13, p = pt & (NPTS - 1);
  ptsT[((size_t)b * 3 + d) * NPTS + p] = pts[gid];
}

// ---------------------------------------------------------------------------
// K1: pointwise conv 3->64 + relu
// ---------------------------------------------------------------------------
__global__ __launch_bounds__(256) void k_conv(const float* __restrict__ pts,
                                              const float* __restrict__ w,
                                              const float* __restrict__ b,
                                              float* __restrict__ x0) {
  int gid = blockIdx.x * 256 + threadIdx.x;
  if (gid >= TOTAL * 64) return;
  int p = gid >> 6, c = gid & 63;
  float px = pts[p * 3 + 0], py = pts[p * 3 + 1], pz = pts[p * 3 + 2];
  float acc = b[c] + px * w[c] + py * w[64 + c] + pz * w[128 + c];
  x0[gid] = fmaxf(acc, 0.f);
}

// ---------------------------------------------------------------------------
// K2: KNN v5 (R16, measured 440 µs — unchanged). Barrier-free, no LDS,
// f32-bitonic tau (tight, half the shfl cost of packed-u64). Exact.
// ---------------------------------------------------------------------------
__global__ __launch_bounds__(256) void k_knn(const float* __restrict__ ptsT,
                                             const float* __restrict__ pts,
                                             int* __restrict__ idxbuf) {
  int tid = threadIdx.x;
  int wv = tid >> 6, lane = tid & 63;
  int q = blockIdx.x * 4 + wv;
  int bq = q >> 13;
  const float* px = ptsT + (size_t)bq * 3 * NPTS;
  const float* py = px + NPTS;
  const float* pz = py + NPTS;
  float qx = pts[q * 3 + 0], qy = pts[q * 3 + 1], qz = pts[q * 3 + 2];

  float dist[KNB];
  int id[KNB];
#pragma unroll
  for (int j = 0; j < KNB; j++) { dist[j] = 3.402823466e38f; id[j] = 0; }
  float tau = 3.402823466e38f;

  for (int chunk = 0; chunk < 8; chunk++) {
    if (chunk) {
      float h = dist[0];
#pragma unroll
      for (int k = 2; k <= 64; k <<= 1) {
#pragma unroll
        for (int j = k >> 1; j > 0; j >>= 1) {
          float o = __shfl_xor(h, j);
          bool up = ((lane & k) == 0);
          bool lower = ((lane & j) == 0);
          bool takeMin = (up == lower);
          bool lt = h < o;
          h = (takeMin == lt) ? h : o;
        }
      }
      tau = __shfl(h, 19);
    }

    int base = chunk * 1024;
#pragma unroll 4
    for (int i = 0; i < 16; i++) {
      int c = base + lane + (i << 6);
      float dx = qx - px[c];
      float dy = qy - py[c];
      float dz = qz - pz[c];
      float d2 = __fadd_rn(__fadd_rn(__fmul_rn(dx, dx), __fmul_rn(dy, dy)),
                           __fmul_rn(dz, dz));
      if (d2 <= tau && d2 < dist[KNB - 1]) {
        int cid = c;
#pragma unroll
        for (int j = KNB - 1; j >= 0; j--) {
          bool cj = d2 < dist[j];
          bool cjm1 = (j > 0) && (d2 < dist[j - 1]);
          if (cj) {
            dist[j] = cjm1 ? dist[j - 1] : d2;
            id[j]   = cjm1 ? id[j - 1]   : cid;
          }
        }
      }
    }
  }

  int bqoff = bq * NPTS;
  for (int step = 0; step < KNB; step++) {
    unsigned long long p =
        ((unsigned long long)__float_as_uint(dist[0]) << 32) | (unsigned)id[0];
    unsigned long long m = p;
#pragma unroll
    for (int off = 32; off >= 1; off >>= 1) {
      unsigned long long o = __shfl_xor(m, off);
      m = (o < m) ? o : m;
    }
    if (lane == 0) idxbuf[q * KNB + step] = bqoff + (int)(m & 0xffffffffULL);
    if (p == m) {
#pragma unroll
      for (int j = 0; j < KNB - 1; j++) { dist[j] = dist[j + 1]; id[j] = id[j + 1]; }
      dist[KNB - 1] = 3.402823466e38f;
    }
  }
}

// ---------------------------------------------------------------------------
// K3: FUSED qkv + kh (R16, unchanged — proven).
// ---------------------------------------------------------------------------
__global__ __launch_bounds__(256) void k_pre(const float* __restrict__ x,
                                             const float* __restrict__ w,
                                             const float* __restrict__ aw1,
                                             float* __restrict__ qkv,
                                             float* __restrict__ kh) {
  int tid = threadIdx.x;
  int wv = tid >> 6, lane = tid & 63;
  int p = blockIdx.x * 4 + wv;
  const float* xr = x + (size_t)p * 64;

  float qa = 0.f, ka = 0.f, va = 0.f;
#pragma unroll 8
  for (int h = 0; h < 64; h++) {
    float xv = xr[h];
    qa += xv * w[h * 192 + lane];
    ka += xv * w[h * 192 + 64 + lane];
    va += xv * w[h * 192 + 128 + lane];
  }
  qkv[(size_t)p * 192 + lane] = qa;
  qkv[(size_t)p * 192 + 128 + lane] = va;

#define RL(x_, l_) __uint_as_float(__builtin_amdgcn_readlane(__float_as_uint(x_), (l_)))
  int c4 = lane * 4;
  float4 a = make_float4(0.f, 0.f, 0.f, 0.f);
#pragma unroll 8
  for (int h = 0; h < 64; h++) {
    float kb = RL(ka, h);
    float4 wv4 = *(const float4*)&aw1[(size_t)h * 256 + c4];
    a.x += kb * wv4.x; a.y += kb * wv4.y; a.z += kb * wv4.z; a.w += kb * wv4.w;
  }
#undef RL
  *(float4*)&kh[(size_t)p * 256 + c4] = a;
}

// ---------------------------------------------------------------------------
// K3c: per-layer weight folding (once per layer, 65 blocks, ~3 µs):
//   W2[h][c] = sum_j pw2[h][j] * aw1[64+j][c]   (64x256)
//   c0[c]    = sum_j pb2[j]    * aw1[64+j][c]   (256)
// Validity: rpe@aw1_bot = (t1@pw2 + pb2)@aw1_bot = t1@W2 + c0
// (associativity; fp32 reassociation error ~1e-8 << 9.9e-4 threshold).
// ---------------------------------------------------------------------------
__global__ __launch_bounds__(256) void k_w2(const float* __restrict__ pw2,
                                            const float* __restrict__ pb2,
                                            const float* __restrict__ aw1,
                                            float* __restrict__ W2,
                                            float* __restrict__ c0) {
  int h = blockIdx.x, c = threadIdx.x;
  float a = 0.f;
  if (h < 64) {
#pragma unroll 8
    for (int j = 0; j < 64; j++)
      a += pw2[h * 64 + j] * aw1[(size_t)(64 + j) * 256 + c];
    W2[h * 256 + c] = a;
  } else {
#pragma unroll 8
    for (int j = 0; j < 64; j++)
      a += pb2[j] * aw1[(size_t)(64 + j) * 256 + c];
    c0[c] = a;
  }
}

// ---------------------------------------------------------------------------
// K4: wave-per-query attention — R16 STRUCTURE (proven to run) with the
// W2 algebra folded in:
//   - A2 eliminated: hidden = qh - kh[g] + t1@W2 + c0 (t1 staged in LDS,
//     read b128 exactly like R16 read s_rpe; NO dynamic register indexing —
//     R17's t1[nb0+n] under a non-unrolled pass loop was the one unproven
//     pattern and coincided with 2x container failure).
//   - phase C factorized: out = sum an*v_g + (sum an*t1_n)@pw2 + pb2
//     (rpe never materialized; readlane-dot pattern proven in k_pre).
//  Block-uniform barriers only (R9/R10); no min-waves launch-bounds (R5).
// ---------------------------------------------------------------------------
__global__ __launch_bounds__(256) void k_attn(
    const float* __restrict__ pos, const float* __restrict__ qkv,
    const int* __restrict__ idxbuf, const float* __restrict__ kh,
    const float* __restrict__ pw1, const float* __restrict__ pb1,
    const float* __restrict__ pw2, const float* __restrict__ pb2,
    const float* __restrict__ aw1, const float* __restrict__ W2,
    const float* __restrict__ c0, const float* __restrict__ ab1,
    const float* __restrict__ aw2, const float* __restrict__ ab2,
    float* __restrict__ xout) {
  __shared__ float s_t1[4][KNB][64];   // 20 KB: [wave][n][h]
  __shared__ float s_sim[4][KNB];
  __shared__ int   s_nb[4][24];

  int tid = threadIdx.x;
  int wv = tid >> 6, lane = tid & 63;
  int i = blockIdx.x * 4 + wv;

  if (lane < KNB) s_nb[wv][lane] = idxbuf[i * KNB + lane];
  float qv = qkv[(size_t)i * 192 + lane];    // q row, distributed by lane
  float px = pos[i * 3 + 0], py = pos[i * 3 + 1], pz = pos[i * 3 + 2];
  __syncthreads();

#define RL(x, l) __uint_as_float(__builtin_amdgcn_readlane(__float_as_uint(x), (l)))
  // A1: t1[n] = relu(rel . pw1[:,lane] + pb1[lane]) -> registers + LDS
  float t1[KNB];
  {
    float w1x = pw1[lane], w1y = pw1[64 + lane], w1z = pw1[128 + lane];
    float b1h = pb1[lane];
#pragma unroll
    for (int n = 0; n < KNB; n++) {
      int g = s_nb[wv][n];
      float rx = px - pos[g * 3 + 0];
      float ry = py - pos[g * 3 + 1];
      float rz = pz - pos[g * 3 + 2];
      t1[n] = fmaxf(b1h + rx * w1x + ry * w1y + rz * w1z, 0.f);
      s_t1[wv][n][lane] = t1[n];
    }
  }
  __syncthreads();

  // qh (once per query): q . aw1_top[:,col] + c0, lane owns cols 4*lane..+3
  int col0 = lane * 4;
  float4 qh4 = make_float4(0.f, 0.f, 0.f, 0.f);
#pragma unroll 8
  for (int k = 0; k < 64; k++) {
    float qk = RL(qv, k);
    float4 w = *(const float4*)&aw1[(size_t)k * 256 + col0];
    qh4.x += qk * w.x; qh4.y += qk * w.y; qh4.z += qk * w.z; qh4.w += qk * w.w;
  }
  {
    float4 c04 = *(const float4*)&c0[col0];
    qh4.x += c04.x; qh4.y += c04.y; qh4.z += c04.z; qh4.w += c04.w;
  }

  // B: 4 sequential passes of 5 neighbors (R16 shape); hidden =
  // qh4 - kh[g] + t1@W2, t1 rows read from LDS as b128.
  float4 b1v = *(const float4*)&ab1[col0];
  float4 w2v = *(const float4*)&aw2[col0];
  float ab2v = ab2[0];
#pragma unroll 1
  for (int pass = 0; pass < 4; pass++) {
    int nb0 = pass * 5;
    float acc[5][4];
#pragma unroll
    for (int n = 0; n < 5; n++) {
      int g = s_nb[wv][nb0 + n];
      float4 kv = *(const float4*)&kh[(size_t)g * 256 + col0];
      acc[n][0] = qh4.x - kv.x; acc[n][1] = qh4.y - kv.y;
      acc[n][2] = qh4.z - kv.z; acc[n][3] = qh4.w - kv.w;
    }
#pragma unroll 2
    for (int kc = 0; kc < 64; kc += 4) {
      float4 w0 = *(const float4*)&W2[(kc + 0) * 256 + col0];
      float4 w1 = *(const float4*)&W2[(kc + 1) * 256 + col0];
      float4 w2 = *(const float4*)&W2[(kc + 2) * 256 + col0];
      float4 w3 = *(const float4*)&W2[(kc + 3) * 256 + col0];
#pragma unroll
      for (int n = 0; n < 5; n++) {
        float4 iv = *(float4*)&s_t1[wv][nb0 + n][kc];
        acc[n][0] += iv.x * w0.x + iv.y * w1.x + iv.z * w2.x + iv.w * w3.x;
        acc[n][1] += iv.x * w0.y + iv.y * w1.y + iv.z * w2.y + iv.w * w3.y;
        acc[n][2] += iv.x * w0.z + iv.y * w1.z + iv.z * w2.z + iv.w * w3.z;
        acc[n][3] += iv.x * w0.w + iv.y * w1.w + iv.z * w2.w + iv.w * w3.w;
      }
    }
#pragma unroll
    for (int n = 0; n < 5; n++) {
      float s = fmaxf(acc[n][0] + b1v.x, 0.f) * w2v.x +
                fmaxf(acc[n][1] + b1v.y, 0.f) * w2v.y +
                fmaxf(acc[n][2] + b1v.z, 0.f) * w2v.z +
                fmaxf(acc[n][3] + b1v.w, 0.f) * w2v.w;
#pragma unroll
      for (int off = 32; off >= 1; off >>= 1) s += __shfl_xor(s, off);
      if (lane == 0) s_sim[wv][nb0 + n] = s + ab2v;
    }
  }
  __syncthreads();

  // C: softmax; out = sum an*v_g + (sum an*t1_n)@pw2 + pb2
  float mx = -3.402823466e38f;
#pragma unroll
  for (int n = 0; n < KNB; n++) mx = fmaxf(mx, s_sim[wv][n]);
  float sum = 0.f;
#pragma unroll
  for (int n = 0; n < KNB; n++) sum += expf(s_sim[wv][n] - mx);
  float inv = 1.f / sum;
  float o = 0.f;        // sum an * v_g[lane]
  float sac = 0.f;      // sum an * t1[n]  (channel = lane)
#pragma unroll
  for (int n = 0; n < KNB; n++) {
    int g = s_nb[wv][n];
    float an = expf(s_sim[wv][n] - mx) * inv;
    o += an * qkv[(size_t)g * 192 + 128 + lane];
    sac += an * t1[n];
  }
  float r = pb2[lane];
#pragma unroll 8
  for (int j = 0; j < 64; j++) r += RL(sac, j) * pw2[j * 64 + lane];
#undef RL
  xout[(size_t)i * 64 + lane] = o + r;
}

// ---------------------------------------------------------------------------
// K5: global max-pool + fc1 + fc3 (unchanged)
// ---------------------------------------------------------------------------
__global__ __launch_bounds__(256) void k_final(const float* __restrict__ x,
                                               const float* __restrict__ fc1w,
                                               const float* __restrict__ fc1b,
                                               const float* __restrict__ fc3w,
                                               const float* __restrict__ fc3b,
                                               float* __restrict__ out) {
  __shared__ float red[4][64];
  __shared__ float m[64];
  __shared__ float h1[32];
  int b = blockIdx.x;
  int tid = threadIdx.x;
  int c = tid & 63, pg = tid >> 6;
  float mx = -3.402823466e38f;
  for (int p = pg; p < NPTS; p += 4)
    mx = fmaxf(mx, x[((size_t)b * NPTS + p) * 64 + c]);
  red[pg][c] = mx;
  __syncthreads();
  if (tid < 64)
    m[c] = fmaxf(fmaxf(red[0][c], red[1][c]), fmaxf(red[2][c], red[3][c]));
  __syncthreads();
  if (tid < 32) {
    float a = fc1b[tid];
#pragma unroll 8
    for (int k = 0; k < 64; k++) a += m[k] * fc1w[k * 32 + tid];
    h1[tid] = fmaxf(a, 0.f);
  }
  __syncthreads();
  if (tid < 3) {
    float a = fc3b[tid];
#pragma unroll
    for (int k = 0; k < 32; k++) a += h1[k] * fc3w[k * 3 + tid];
    out[b * 3 + tid] = a;
  }
}

// ---------------------------------------------------------------------------
// Workspace (peak 36.2 MB):
//   idx @ 0 (1.31MB) | ptsT @ 1.5MB (0.2MB) | W2 @ 1.75MB (64KB) |
//   c0 @ 1.82MB (1KB) | qkv @ 2MB (12.6MB) | kh @ 15MB (16.8MB) |
//   act @ 32MB (4.2MB, x0/x1/x2 share)
// ---------------------------------------------------------------------------
extern "C" void kernel_launch(void* const* d_in, const int* in_sizes, int n_in,
                              void* d_out, int out_size, void* d_ws,
                              size_t ws_size, hipStream_t stream) {
  const float* pts    = (const float*)d_in[0];
  const float* conv_w = (const float*)d_in[1];
  const float* conv_b = (const float*)d_in[2];
  const float* fc1w = (const float*)d_in[21];
  const float* fc1b = (const float*)d_in[22];
  const float* fc3w = (const float*)d_in[23];
  const float* fc3b = (const float*)d_in[24];
  float* outp = (float*)d_out;

  char* ws = (char*)d_ws;
  int*   idx  = (int*)  (ws);
  float* ptsT = (float*)(ws + (size_t)1536 * 1024);
  float* W2   = (float*)(ws + (size_t)1792 * 1024);
  float* c0   = (float*)(ws + (size_t)1862 * 1024);
  float* qkv  = (float*)(ws + (size_t)2 * 1048576);
  float* kh   = (float*)(ws + (size_t)15 * 1048576);
  float* act  = (float*)(ws + (size_t)32 * 1048576);

  k_pose<<<(TOTAL * 3 + 255) / 256, 256, 0, stream>>>(pts, ptsT);
  k_conv<<<(TOTAL * 64 + 255) / 256, 256, 0, stream>>>(pts, conv_w, conv_b, act);
  k_knn<<<TOTAL / 4, 256, 0, stream>>>(ptsT, pts, idx);

  for (int layer = 0; layer < 2; layer++) {
    int base = 3 + layer * 9;
    const float* qkvw = (const float*)d_in[base + 0];
    const float* pw1  = (const float*)d_in[base + 1];
    const float* pb1  = (const float*)d_in[base + 2];
    const float* pw2  = (const float*)d_in[base + 3];
    const float* pb2  = (const float*)d_in[base + 4];
    const float* aw1  = (const float*)d_in[base + 5];
    const float* ab1  = (const float*)d_in[base + 6];
    const float* aw2  = (const float*)d_in[base + 7];
    const float* ab2  = (const float*)d_in[base + 8];
    k_pre<<<TOTAL / 4, 256, 0, stream>>>(act, qkvw, aw1, qkv, kh);
    k_w2<<<65, 256, 0, stream>>>(pw2, pb2, aw1, W2, c0);
    k_attn<<<TOTAL / 4, 256, 0, stream>>>(
        pts, qkv, idx, kh, pw1, pb1, pw2, pb2, aw1, W2, c0, ab1, aw2, ab2,
        act);
  }
  k_final<<<BATCH, 256, 0, stream>>>(act, fc1w, fc1b, fc3w, fc3b, outp);
}

// Round 19
// 1334.886 us; speedup vs baseline: 1.2865x; 1.0894x over previous
//
#include <hip/hip_runtime.h>
#include <cstdint>
#include <cstddef>

#define KNB 20
#define NPTS 8192
#define BATCH 2
#define TOTAL (BATCH * NPTS)

// ---------------------------------------------------------------------------
// K0: transpose pts to SoA for coalesced, L1-hot KNN candidate reads.
// ---------------------------------------------------------------------------
__global__ __launch_bounds__(256) void k_pose(const float* __restrict__ pts,
                                              float* __restrict__ ptsT) {
  int gid = blockIdx.x * 256 + threadIdx.x;
  if (gid >= TOTAL * 3) return;
  int pt = gid / 3, d = gid % 3;
  int b = pt >> 13, p = pt & (NPTS - 1);
  ptsT[((size_t)b * 3 + d) * NPTS + p] = pts[gid];
}

// ---------------------------------------------------------------------------
// K1: pointwise conv 3->64 + relu
// ---------------------------------------------------------------------------
__global__ __launch_bounds__(256) void k_conv(const float* __restrict__ pts,
                                              const float* __restrict__ w,
                                              const float* __restrict__ b,
                                              float* __restrict__ x0) {
  int gid = blockIdx.x * 256 + threadIdx.x;
  if (gid >= TOTAL * 64) return;
  int p = gid >> 6, c = gid & 63;
  float px = pts[p * 3 + 0], py = pts[p * 3 + 1], pz = pts[p * 3 + 2];
  float acc = b[c] + px * w[c] + py * w[64 + c] + pz * w[128 + c];
  x0[gid] = fmaxf(acc, 0.f);
}

// ---------------------------------------------------------------------------
// K2: KNN v6 — barrier-free, no LDS, f32-bitonic tau (R16/R18 proven) +
// FLOAT4 candidate loads: lane owns 4 consecutive candidates per group
// (12 load instr/chunk instead of 48; 4-way independent d2 ILP). The
// lane->candidate remap does not affect exactness: the final merge is a
// global min-extract over packed (d2bits, cid).
// d2 via __fmul_rn/__fadd_rn: bit-identical to numpy's ((dx²+dy²)+dz²).
// ---------------------------------------------------------------------------
__global__ __launch_bounds__(256) void k_knn(const float* __restrict__ ptsT,
                                             const float* __restrict__ pts,
                                             int* __restrict__ idxbuf) {
  int tid = threadIdx.x;
  int wv = tid >> 6, lane = tid & 63;
  int q = blockIdx.x * 4 + wv;
  int bq = q >> 13;
  const float* px = ptsT + (size_t)bq * 3 * NPTS;
  const float* py = px + NPTS;
  const float* pz = py + NPTS;
  float qx = pts[q * 3 + 0], qy = pts[q * 3 + 1], qz = pts[q * 3 + 2];

  float dist[KNB];
  int id[KNB];
#pragma unroll
  for (int j = 0; j < KNB; j++) { dist[j] = 3.402823466e38f; id[j] = 0; }
  float tau = 3.402823466e38f;

#define INSERT(D2, CID)                                                      \
  if ((D2) <= tau && (D2) < dist[KNB - 1]) {                                 \
    int cid_ = (CID);                                                        \
    _Pragma("unroll")                                                        \
    for (int j = KNB - 1; j >= 0; j--) {                                     \
      bool cj = (D2) < dist[j];                                              \
      bool cjm1 = (j > 0) && ((D2) < dist[j - 1]);                           \
      if (cj) {                                                              \
        dist[j] = cjm1 ? dist[j - 1] : (D2);                                 \
        id[j]   = cjm1 ? id[j - 1]   : cid_;                                 \
      }                                                                      \
    }                                                                        \
  }

  for (int chunk = 0; chunk < 8; chunk++) {
    if (chunk) {
      // tau = 20th smallest of the 64 lane-head d2 values (f32 bitonic).
      float h = dist[0];
#pragma unroll
      for (int k = 2; k <= 64; k <<= 1) {
#pragma unroll
        for (int j = k >> 1; j > 0; j >>= 1) {
          float o = __shfl_xor(h, j);
          bool up = ((lane & k) == 0);
          bool lower = ((lane & j) == 0);
          bool takeMin = (up == lower);
          bool lt = h < o;
          h = (takeMin == lt) ? h : o;
        }
      }
      tau = __shfl(h, 19);
    }

    int base = chunk * 1024;
#pragma unroll
    for (int g = 0; g < 4; g++) {
      int cb = base + g * 256 + lane * 4;
      float4 x4 = *(const float4*)&px[cb];
      float4 y4 = *(const float4*)&py[cb];
      float4 z4 = *(const float4*)&pz[cb];
      float dx0 = qx - x4.x, dy0 = qy - y4.x, dz0 = qz - z4.x;
      float dx1 = qx - x4.y, dy1 = qy - y4.y, dz1 = qz - z4.y;
      float dx2 = qx - x4.z, dy2 = qy - y4.z, dz2 = qz - z4.z;
      float dx3 = qx - x4.w, dy3 = qy - y4.w, dz3 = qz - z4.w;
      float d0 = __fadd_rn(__fadd_rn(__fmul_rn(dx0, dx0), __fmul_rn(dy0, dy0)),
                           __fmul_rn(dz0, dz0));
      float d1 = __fadd_rn(__fadd_rn(__fmul_rn(dx1, dx1), __fmul_rn(dy1, dy1)),
                           __fmul_rn(dz1, dz1));
      float d2v = __fadd_rn(__fadd_rn(__fmul_rn(dx2, dx2), __fmul_rn(dy2, dy2)),
                            __fmul_rn(dz2, dz2));
      float d3 = __fadd_rn(__fadd_rn(__fmul_rn(dx3, dx3), __fmul_rn(dy3, dy3)),
                           __fmul_rn(dz3, dz3));
      INSERT(d0, cb + 0)
      INSERT(d1, cb + 1)
      INSERT(d2v, cb + 2)
      INSERT(d3, cb + 3)
    }
  }
#undef INSERT

  // 20-step cross-lane merge: min over packed (d2bits, cid) — exact
  // lax.top_k order (d2 asc, index asc).
  int bqoff = bq * NPTS;
  for (int step = 0; step < KNB; step++) {
    unsigned long long p =
        ((unsigned long long)__float_as_uint(dist[0]) << 32) | (unsigned)id[0];
    unsigned long long m = p;
#pragma unroll
    for (int off = 32; off >= 1; off >>= 1) {
      unsigned long long o = __shfl_xor(m, off);
      m = (o < m) ? o : m;
    }
    if (lane == 0) idxbuf[q * KNB + step] = bqoff + (int)(m & 0xffffffffULL);
    if (p == m) {
#pragma unroll
      for (int j = 0; j < KNB - 1; j++) { dist[j] = dist[j + 1]; id[j] = id[j + 1]; }
      dist[KNB - 1] = 3.402823466e38f;
    }
  }
}

// ---------------------------------------------------------------------------
// K3c: per-layer weight folding (once per layer, 65 blocks, ~3 µs):
//   W2[h][c] = sum_j pw2[h][j] * aw1[64+j][c];  c0[c] = sum_j pb2[j]*aw1[64+j][c]
// Validity: rpe@aw1_bot = (t1@pw2 + pb2)@aw1_bot = t1@W2 + c0.
// ---------------------------------------------------------------------------
__global__ __launch_bounds__(256) void k_w2(const float* __restrict__ pw2,
                                            const float* __restrict__ pb2,
                                            const float* __restrict__ aw1,
                                            float* __restrict__ W2,
                                            float* __restrict__ c0) {
  int h = blockIdx.x, c = threadIdx.x;
  float a = 0.f;
  if (h < 64) {
#pragma unroll 8
    for (int j = 0; j < 64; j++)
      a += pw2[h * 64 + j] * aw1[(size_t)(64 + j) * 256 + c];
    W2[h * 256 + c] = a;
  } else {
#pragma unroll 8
    for (int j = 0; j < 64; j++)
      a += pb2[j] * aw1[(size_t)(64 + j) * 256 + c];
    c0[c] = a;
  }
}

// ---------------------------------------------------------------------------
// K3: FUSED qkv + kh + qh (wave per point). q/k live only in registers:
//   v[p]   = x@Wv                       (only qkv slice attn still needs)
//   kh[p]  = (x@Wk) @ aw1_top           (readlane pattern, proven R16)
//   qh[p]  = (x@Wq) @ aw1_top + c0      (same accumulation order as R18's
//            in-attn qh loop -> bit-identical; saves ~270 instr/attn-wave)
// ---------------------------------------------------------------------------
__global__ __launch_bounds__(256) void k_pre(const float* __restrict__ x,
                                             const float* __restrict__ w,
                                             const float* __restrict__ aw1,
                                             const float* __restrict__ c0,
                                             float* __restrict__ v,
                                             float* __restrict__ kh,
                                             float* __restrict__ qh) {
  int tid = threadIdx.x;
  int wv = tid >> 6, lane = tid & 63;
  int p = blockIdx.x * 4 + wv;
  const float* xr = x + (size_t)p * 64;

  float qa = 0.f, ka = 0.f, va = 0.f;
#pragma unroll 8
  for (int h = 0; h < 64; h++) {
    float xv = xr[h];
    qa += xv * w[h * 192 + lane];
    ka += xv * w[h * 192 + 64 + lane];
    va += xv * w[h * 192 + 128 + lane];
  }
  v[(size_t)p * 64 + lane] = va;

#define RL(x_, l_) __uint_as_float(__builtin_amdgcn_readlane(__float_as_uint(x_), (l_)))
  int c4 = lane * 4;
  float4 a = make_float4(0.f, 0.f, 0.f, 0.f);
#pragma unroll 8
  for (int h = 0; h < 64; h++) {
    float kb = RL(ka, h);
    float4 wv4 = *(const float4*)&aw1[(size_t)h * 256 + c4];
    a.x += kb * wv4.x; a.y += kb * wv4.y; a.z += kb * wv4.z; a.w += kb * wv4.w;
  }
  *(float4*)&kh[(size_t)p * 256 + c4] = a;

  float4 b = make_float4(0.f, 0.f, 0.f, 0.f);
#pragma unroll 8
  for (int h = 0; h < 64; h++) {
    float qb = RL(qa, h);
    float4 wv4 = *(const float4*)&aw1[(size_t)h * 256 + c4];
    b.x += qb * wv4.x; b.y += qb * wv4.y; b.z += qb * wv4.z; b.w += qb * wv4.w;
  }
#undef RL
  float4 c04 = *(const float4*)&c0[c4];
  b.x += c04.x; b.y += c04.y; b.z += c04.z; b.w += c04.w;
  *(float4*)&qh[(size_t)p * 256 + c4] = b;
}

// ---------------------------------------------------------------------------
// K4: wave-per-query attention (R18 structure; qh precomputed; pass loop
// FULLY unrolled — nb0 is compile-time 0/5/10/15, so all register indices
// stay static (R4/R17 trap avoided) and the scheduler can hoist pass p+1's
// kh gathers under pass p's FMA stream).
//   hidden = qh[i] - kh[g] + t1@W2      (A2 eliminated via W2 folding)
//   out    = sum an*v_g + (sum an*t1_n)@pw2 + pb2
//  Block-uniform barriers only (R9/R10); no min-waves launch-bounds (R5).
// ---------------------------------------------------------------------------
__global__ __launch_bounds__(256) void k_attn(
    const float* __restrict__ pos, const float* __restrict__ v,
    const int* __restrict__ idxbuf, const float* __restrict__ kh,
    const float* __restrict__ qh,
    const float* __restrict__ pw1, const float* __restrict__ pb1,
    const float* __restrict__ pw2, const float* __restrict__ pb2,
    const float* __restrict__ W2, const float* __restrict__ ab1,
    const float* __restrict__ aw2, const float* __restrict__ ab2,
    float* __restrict__ xout) {
  __shared__ float s_t1[4][KNB][64];   // 20 KB: [wave][n][h]
  __shared__ float s_sim[4][KNB];
  __shared__ int   s_nb[4][24];

  int tid = threadIdx.x;
  int wv = tid >> 6, lane = tid & 63;
  int i = blockIdx.x * 4 + wv;

  if (lane < KNB) s_nb[wv][lane] = idxbuf[i * KNB + lane];
  float px = pos[i * 3 + 0], py = pos[i * 3 + 1], pz = pos[i * 3 + 2];
  __syncthreads();

#define RL(x, l) __uint_as_float(__builtin_amdgcn_readlane(__float_as_uint(x), (l)))
  // A1: t1[n] = relu(rel . pw1[:,lane] + pb1[lane]) -> registers + LDS
  float t1[KNB];
  {
    float w1x = pw1[lane], w1y = pw1[64 + lane], w1z = pw1[128 + lane];
    float b1h = pb1[lane];
#pragma unroll
    for (int n = 0; n < KNB; n++) {
      int g = s_nb[wv][n];
      float rx = px - pos[g * 3 + 0];
      float ry = py - pos[g * 3 + 1];
      float rz = pz - pos[g * 3 + 2];
      t1[n] = fmaxf(b1h + rx * w1x + ry * w1y + rz * w1z, 0.f);
      s_t1[wv][n][lane] = t1[n];
    }
  }
  __syncthreads();

  // qh: one float4 load (precomputed in k_pre, includes c0)
  int col0 = lane * 4;
  float4 qh4 = *(const float4*)&qh[(size_t)i * 256 + col0];

  // B: 4 fully-unrolled passes of 5 neighbors; hidden = qh4 - kh[g] + t1@W2.
  float4 b1v = *(const float4*)&ab1[col0];
  float4 w2v = *(const float4*)&aw2[col0];
  float ab2v = ab2[0];
#pragma unroll
  for (int pass = 0; pass < 4; pass++) {
    int nb0 = pass * 5;     // compile-time constant per unrolled copy
    float acc[5][4];
#pragma unroll
    for (int n = 0; n < 5; n++) {
      int g = s_nb[wv][nb0 + n];
      float4 kv = *(const float4*)&kh[(size_t)g * 256 + col0];
      acc[n][0] = qh4.x - kv.x; acc[n][1] = qh4.y - kv.y;
      acc[n][2] = qh4.z - kv.z; acc[n][3] = qh4.w - kv.w;
    }
#pragma unroll 2
    for (int kc = 0; kc < 64; kc += 4) {
      float4 w0 = *(const float4*)&W2[(kc + 0) * 256 + col0];
      float4 w1 = *(const float4*)&W2[(kc + 1) * 256 + col0];
      float4 w2 = *(const float4*)&W2[(kc + 2) * 256 + col0];
      float4 w3 = *(const float4*)&W2[(kc + 3) * 256 + col0];
#pragma unroll
      for (int n = 0; n < 5; n++) {
        float4 iv = *(float4*)&s_t1[wv][nb0 + n][kc];
        acc[n][0] += iv.x * w0.x + iv.y * w1.x + iv.z * w2.x + iv.w * w3.x;
        acc[n][1] += iv.x * w0.y + iv.y * w1.y + iv.z * w2.y + iv.w * w3.y;
        acc[n][2] += iv.x * w0.z + iv.y * w1.z + iv.z * w2.z + iv.w * w3.z;
        acc[n][3] += iv.x * w0.w + iv.y * w1.w + iv.z * w2.w + iv.w * w3.w;
      }
    }
#pragma unroll
    for (int n = 0; n < 5; n++) {
      float s = fmaxf(acc[n][0] + b1v.x, 0.f) * w2v.x +
                fmaxf(acc[n][1] + b1v.y, 0.f) * w2v.y +
                fmaxf(acc[n][2] + b1v.z, 0.f) * w2v.z +
                fmaxf(acc[n][3] + b1v.w, 0.f) * w2v.w;
#pragma unroll
      for (int off = 32; off >= 1; off >>= 1) s += __shfl_xor(s, off);
      if (lane == 0) s_sim[wv][nb0 + n] = s + ab2v;
    }
  }
  __syncthreads();

  // C: softmax; out = sum an*v_g + (sum an*t1_n)@pw2 + pb2
  float mx = -3.402823466e38f;
#pragma unroll
  for (int n = 0; n < KNB; n++) mx = fmaxf(mx, s_sim[wv][n]);
  float sum = 0.f;
#pragma unroll
  for (int n = 0; n < KNB; n++) sum += expf(s_sim[wv][n] - mx);
  float inv = 1.f / sum;
  float o = 0.f;        // sum an * v_g[lane]
  float sac = 0.f;      // sum an * t1[n]  (channel = lane)
#pragma unroll
  for (int n = 0; n < KNB; n++) {
    int g = s_nb[wv][n];
    float an = expf(s_sim[wv][n] - mx) * inv;
    o += an * v[(size_t)g * 64 + lane];
    sac += an * t1[n];
  }
  float r = pb2[lane];
#pragma unroll 8
  for (int j = 0; j < 64; j++) r += RL(sac, j) * pw2[j * 64 + lane];
#undef RL
  xout[(size_t)i * 64 + lane] = o + r;
}

// ---------------------------------------------------------------------------
// K5: global max-pool + fc1 + fc3 (unchanged)
// ---------------------------------------------------------------------------
__global__ __launch_bounds__(256) void k_final(const float* __restrict__ x,
                                               const float* __restrict__ fc1w,
                                               const float* __restrict__ fc1b,
                                               const float* __restrict__ fc3w,
                                               const float* __restrict__ fc3b,
                                               float* __restrict__ out) {
  __shared__ float red[4][64];
  __shared__ float m[64];
  __shared__ float h1[32];
  int b = blockIdx.x;
  int tid = threadIdx.x;
  int c = tid & 63, pg = tid >> 6;
  float mx = -3.402823466e38f;
  for (int p = pg; p < NPTS; p += 4)
    mx = fmaxf(mx, x[((size_t)b * NPTS + p) * 64 + c]);
  red[pg][c] = mx;
  __syncthreads();
  if (tid < 64)
    m[c] = fmaxf(fmaxf(red[0][c], red[1][c]), fmaxf(red[2][c], red[3][c]));
  __syncthreads();
  if (tid < 32) {
    float a = fc1b[tid];
#pragma unroll 8
    for (int k = 0; k < 64; k++) a += m[k] * fc1w[k * 32 + tid];
    h1[tid] = fmaxf(a, 0.f);
  }
  __syncthreads();
  if (tid < 3) {
    float a = fc3b[tid];
#pragma unroll
    for (int k = 0; k < 32; k++) a += h1[k] * fc3w[k * 3 + tid];
    out[b * 3 + tid] = a;
  }
}

// ---------------------------------------------------------------------------
// Workspace (peak ~44.8 MB; prior proven 36.2 MB — v-only buffer offsets
// the new qh buffer partially):
//   idx @ 0 (1.31MB) | ptsT @ 1.5MB (0.2MB) | W2 @ 1.75MB (64KB) |
//   c0 @ 1.82MB (1KB) | v @ 2MB (4.2MB) | kh @ 6.5MB (16.8MB) |
//   qh @ 23.5MB (16.8MB) | act @ 40.5MB (4.2MB)
// ---------------------------------------------------------------------------
extern "C" void kernel_launch(void* const* d_in, const int* in_sizes, int n_in,
                              void* d_out, int out_size, void* d_ws,
                              size_t ws_size, hipStream_t stream) {
  const float* pts    = (const float*)d_in[0];
  const float* conv_w = (const float*)d_in[1];
  const float* conv_b = (const float*)d_in[2];
  const float* fc1w = (const float*)d_in[21];
  const float* fc1b = (const float*)d_in[22];
  const float* fc3w = (const float*)d_in[23];
  const float* fc3b = (const float*)d_in[24];
  float* outp = (float*)d_out;

  char* ws = (char*)d_ws;
  int*   idx  = (int*)  (ws);
  float* ptsT = (float*)(ws + (size_t)1536 * 1024);
  float* W2   = (float*)(ws + (size_t)1792 * 1024);
  float* c0   = (float*)(ws + (size_t)1862 * 1024);
  float* v    = (float*)(ws + (size_t)2 * 1048576);
  float* kh   = (float*)(ws + (size_t)6656 * 1024);
  float* qh   = (float*)(ws + (size_t)24064 * 1024);
  float* act  = (float*)(ws + (size_t)41472 * 1024);

  k_pose<<<(TOTAL * 3 + 255) / 256, 256, 0, stream>>>(pts, ptsT);
  k_conv<<<(TOTAL * 64 + 255) / 256, 256, 0, stream>>>(pts, conv_w, conv_b, act);
  k_knn<<<TOTAL / 4, 256, 0, stream>>>(ptsT, pts, idx);

  for (int layer = 0; layer < 2; layer++) {
    int base = 3 + layer * 9;
    const float* qkvw = (const float*)d_in[base + 0];
    const float* pw1  = (const float*)d_in[base + 1];
    const float* pb1  = (const float*)d_in[base + 2];
    const float* pw2  = (const float*)d_in[base + 3];
    const float* pb2  = (const float*)d_in[base + 4];
    const float* aw1  = (const float*)d_in[base + 5];
    const float* ab1  = (const float*)d_in[base + 6];
    const float* aw2  = (const float*)d_in[base + 7];
    const float* ab2  = (const float*)d_in[base + 8];
    k_w2<<<65, 256, 0, stream>>>(pw2, pb2, aw1, W2, c0);
    k_pre<<<TOTAL / 4, 256, 0, stream>>>(act, qkvw, aw1, c0, v, kh, qh);
    k_attn<<<TOTAL / 4, 256, 0, stream>>>(
        pts, v, idx, kh, qh, pw1, pb1, pw2, pb2, W2, ab1, aw2, ab2, act);
  }
  k_final<<<BATCH, 256, 0, stream>>>(act, fc1w, fc1b, fc3w, fc3b, outp);
}

// Round 20
// 1027.266 us; speedup vs baseline: 1.6718x; 1.2995x over previous
//
#include <hip/hip_runtime.h>
#include <cstdint>
#include <cstddef>

#define KNB 20
#define NPTS 8192
#define BATCH 2
#define TOTAL (BATCH * NPTS)

// ---------------------------------------------------------------------------
// K0: transpose pts to SoA for coalesced, L1-hot KNN candidate reads.
// ---------------------------------------------------------------------------
__global__ __launch_bounds__(256) void k_pose(const float* __restrict__ pts,
                                              float* __restrict__ ptsT) {
  int gid = blockIdx.x * 256 + threadIdx.x;
  if (gid >= TOTAL * 3) return;
  int pt = gid / 3, d = gid % 3;
  int b = pt >> 13, p = pt & (NPTS - 1);
  ptsT[((size_t)b * 3 + d) * NPTS + p] = pts[gid];
}

// ---------------------------------------------------------------------------
// K1: pointwise conv 3->64 + relu
// ---------------------------------------------------------------------------
__global__ __launch_bounds__(256) void k_conv(const float* __restrict__ pts,
                                              const float* __restrict__ w,
                                              const float* __restrict__ b,
                                              float* __restrict__ x0) {
  int gid = blockIdx.x * 256 + threadIdx.x;
  if (gid >= TOTAL * 64) return;
  int p = gid >> 6, c = gid & 63;
  float px = pts[p * 3 + 0], py = pts[p * 3 + 1], pz = pts[p * 3 + 2];
  float acc = b[c] + px * w[c] + py * w[64 + c] + pz * w[128 + c];
  x0[gid] = fmaxf(acc, 0.f);
}

// ---------------------------------------------------------------------------
// K2: KNN v6 (R19, proven) — barrier-free, no LDS, f32-bitonic tau,
// float4 candidate loads. Exact lax.top_k order.
// ---------------------------------------------------------------------------
__global__ __launch_bounds__(256) void k_knn(const float* __restrict__ ptsT,
                                             const float* __restrict__ pts,
                                             int* __restrict__ idxbuf) {
  int tid = threadIdx.x;
  int wv = tid >> 6, lane = tid & 63;
  int q = blockIdx.x * 4 + wv;
  int bq = q >> 13;
  const float* px = ptsT + (size_t)bq * 3 * NPTS;
  const float* py = px + NPTS;
  const float* pz = py + NPTS;
  float qx = pts[q * 3 + 0], qy = pts[q * 3 + 1], qz = pts[q * 3 + 2];

  float dist[KNB];
  int id[KNB];
#pragma unroll
  for (int j = 0; j < KNB; j++) { dist[j] = 3.402823466e38f; id[j] = 0; }
  float tau = 3.402823466e38f;

#define INSERT(D2, CID)                                                      \
  if ((D2) <= tau && (D2) < dist[KNB - 1]) {                                 \
    int cid_ = (CID);                                                        \
    _Pragma("unroll")                                                        \
    for (int j = KNB - 1; j >= 0; j--) {                                     \
      bool cj = (D2) < dist[j];                                              \
      bool cjm1 = (j > 0) && ((D2) < dist[j - 1]);                           \
      if (cj) {                                                              \
        dist[j] = cjm1 ? dist[j - 1] : (D2);                                 \
        id[j]   = cjm1 ? id[j - 1]   : cid_;                                 \
      }                                                                      \
    }                                                                        \
  }

  for (int chunk = 0; chunk < 8; chunk++) {
    if (chunk) {
      float h = dist[0];
#pragma unroll
      for (int k = 2; k <= 64; k <<= 1) {
#pragma unroll
        for (int j = k >> 1; j > 0; j >>= 1) {
          float o = __shfl_xor(h, j);
          bool up = ((lane & k) == 0);
          bool lower = ((lane & j) == 0);
          bool takeMin = (up == lower);
          bool lt = h < o;
          h = (takeMin == lt) ? h : o;
        }
      }
      tau = __shfl(h, 19);
    }

    int base = chunk * 1024;
#pragma unroll
    for (int g = 0; g < 4; g++) {
      int cb = base + g * 256 + lane * 4;
      float4 x4 = *(const float4*)&px[cb];
      float4 y4 = *(const float4*)&py[cb];
      float4 z4 = *(const float4*)&pz[cb];
      float dx0 = qx - x4.x, dy0 = qy - y4.x, dz0 = qz - z4.x;
      float dx1 = qx - x4.y, dy1 = qy - y4.y, dz1 = qz - z4.y;
      float dx2 = qx - x4.z, dy2 = qy - y4.z, dz2 = qz - z4.z;
      float dx3 = qx - x4.w, dy3 = qy - y4.w, dz3 = qz - z4.w;
      float d0 = __fadd_rn(__fadd_rn(__fmul_rn(dx0, dx0), __fmul_rn(dy0, dy0)),
                           __fmul_rn(dz0, dz0));
      float d1 = __fadd_rn(__fadd_rn(__fmul_rn(dx1, dx1), __fmul_rn(dy1, dy1)),
                           __fmul_rn(dz1, dz1));
      float d2v = __fadd_rn(__fadd_rn(__fmul_rn(dx2, dx2), __fmul_rn(dy2, dy2)),
                            __fmul_rn(dz2, dz2));
      float d3 = __fadd_rn(__fadd_rn(__fmul_rn(dx3, dx3), __fmul_rn(dy3, dy3)),
                           __fmul_rn(dz3, dz3));
      INSERT(d0, cb + 0)
      INSERT(d1, cb + 1)
      INSERT(d2v, cb + 2)
      INSERT(d3, cb + 3)
    }
  }
#undef INSERT

  int bqoff = bq * NPTS;
  for (int step = 0; step < KNB; step++) {
    unsigned long long p =
        ((unsigned long long)__float_as_uint(dist[0]) << 32) | (unsigned)id[0];
    unsigned long long m = p;
#pragma unroll
    for (int off = 32; off >= 1; off >>= 1) {
      unsigned long long o = __shfl_xor(m, off);
      m = (o < m) ? o : m;
    }
    if (lane == 0) idxbuf[q * KNB + step] = bqoff + (int)(m & 0xffffffffULL);
    if (p == m) {
#pragma unroll
      for (int j = 0; j < KNB - 1; j++) { dist[j] = dist[j + 1]; id[j] = id[j + 1]; }
      dist[KNB - 1] = 3.402823466e38f;
    }
  }
}

// ---------------------------------------------------------------------------
// K3c: per-layer weight folding: W2 = pw2@aw1_bot, c0 = pb2@aw1_bot.
// ---------------------------------------------------------------------------
__global__ __launch_bounds__(256) void k_w2(const float* __restrict__ pw2,
                                            const float* __restrict__ pb2,
                                            const float* __restrict__ aw1,
                                            float* __restrict__ W2,
                                            float* __restrict__ c0) {
  int h = blockIdx.x, c = threadIdx.x;
  float a = 0.f;
  if (h < 64) {
#pragma unroll 8
    for (int j = 0; j < 64; j++)
      a += pw2[h * 64 + j] * aw1[(size_t)(64 + j) * 256 + c];
    W2[h * 256 + c] = a;
  } else {
#pragma unroll 8
    for (int j = 0; j < 64; j++)
      a += pb2[j] * aw1[(size_t)(64 + j) * 256 + c];
    c0[c] = a;
  }
}

// ---------------------------------------------------------------------------
// K3: FUSED qkv + kh + qh (R19, proven).
// ---------------------------------------------------------------------------
__global__ __launch_bounds__(256) void k_pre(const float* __restrict__ x,
                                             const float* __restrict__ w,
                                             const float* __restrict__ aw1,
                                             const float* __restrict__ c0,
                                             float* __restrict__ v,
                                             float* __restrict__ kh,
                                             float* __restrict__ qh) {
  int tid = threadIdx.x;
  int wv = tid >> 6, lane = tid & 63;
  int p = blockIdx.x * 4 + wv;
  const float* xr = x + (size_t)p * 64;

  float qa = 0.f, ka = 0.f, va = 0.f;
#pragma unroll 8
  for (int h = 0; h < 64; h++) {
    float xv = xr[h];
    qa += xv * w[h * 192 + lane];
    ka += xv * w[h * 192 + 64 + lane];
    va += xv * w[h * 192 + 128 + lane];
  }
  v[(size_t)p * 64 + lane] = va;

#define RL(x_, l_) __uint_as_float(__builtin_amdgcn_readlane(__float_as_uint(x_), (l_)))
  int c4 = lane * 4;
  float4 a = make_float4(0.f, 0.f, 0.f, 0.f);
#pragma unroll 8
  for (int h = 0; h < 64; h++) {
    float kb = RL(ka, h);
    float4 wv4 = *(const float4*)&aw1[(size_t)h * 256 + c4];
    a.x += kb * wv4.x; a.y += kb * wv4.y; a.z += kb * wv4.z; a.w += kb * wv4.w;
  }
  *(float4*)&kh[(size_t)p * 256 + c4] = a;

  float4 b = make_float4(0.f, 0.f, 0.f, 0.f);
#pragma unroll 8
  for (int h = 0; h < 64; h++) {
    float qb = RL(qa, h);
    float4 wv4 = *(const float4*)&aw1[(size_t)h * 256 + c4];
    b.x += qb * wv4.x; b.y += qb * wv4.y; b.z += qb * wv4.z; b.w += qb * wv4.w;
  }
#undef RL
  float4 c04 = *(const float4*)&c0[c4];
  b.x += c04.x; b.y += c04.y; b.z += c04.z; b.w += c04.w;
  *(float4*)&qh[(size_t)p * 256 + c4] = b;
}

// ---------------------------------------------------------------------------
// K4: wave-per-query attention (R19, proven).
// ---------------------------------------------------------------------------
__global__ __launch_bounds__(256) void k_attn(
    const float* __restrict__ pos, const float* __restrict__ v,
    const int* __restrict__ idxbuf, const float* __restrict__ kh,
    const float* __restrict__ qh,
    const float* __restrict__ pw1, const float* __restrict__ pb1,
    const float* __restrict__ pw2, const float* __restrict__ pb2,
    const float* __restrict__ W2, const float* __restrict__ ab1,
    const float* __restrict__ aw2, const float* __restrict__ ab2,
    float* __restrict__ xout) {
  __shared__ float s_t1[4][KNB][64];   // 20 KB: [wave][n][h]
  __shared__ float s_sim[4][KNB];
  __shared__ int   s_nb[4][24];

  int tid = threadIdx.x;
  int wv = tid >> 6, lane = tid & 63;
  int i = blockIdx.x * 4 + wv;

  if (lane < KNB) s_nb[wv][lane] = idxbuf[i * KNB + lane];
  float px = pos[i * 3 + 0], py = pos[i * 3 + 1], pz = pos[i * 3 + 2];
  __syncthreads();

#define RL(x, l) __uint_as_float(__builtin_amdgcn_readlane(__float_as_uint(x), (l)))
  float t1[KNB];
  {
    float w1x = pw1[lane], w1y = pw1[64 + lane], w1z = pw1[128 + lane];
    float b1h = pb1[lane];
#pragma unroll
    for (int n = 0; n < KNB; n++) {
      int g = s_nb[wv][n];
      float rx = px - pos[g * 3 + 0];
      float ry = py - pos[g * 3 + 1];
      float rz = pz - pos[g * 3 + 2];
      t1[n] = fmaxf(b1h + rx * w1x + ry * w1y + rz * w1z, 0.f);
      s_t1[wv][n][lane] = t1[n];
    }
  }
  __syncthreads();

  int col0 = lane * 4;
  float4 qh4 = *(const float4*)&qh[(size_t)i * 256 + col0];

  float4 b1v = *(const float4*)&ab1[col0];
  float4 w2v = *(const float4*)&aw2[col0];
  float ab2v = ab2[0];
#pragma unroll
  for (int pass = 0; pass < 4; pass++) {
    int nb0 = pass * 5;
    float acc[5][4];
#pragma unroll
    for (int n = 0; n < 5; n++) {
      int g = s_nb[wv][nb0 + n];
      float4 kv = *(const float4*)&kh[(size_t)g * 256 + col0];
      acc[n][0] = qh4.x - kv.x; acc[n][1] = qh4.y - kv.y;
      acc[n][2] = qh4.z - kv.z; acc[n][3] = qh4.w - kv.w;
    }
#pragma unroll 2
    for (int kc = 0; kc < 64; kc += 4) {
      float4 w0 = *(const float4*)&W2[(kc + 0) * 256 + col0];
      float4 w1 = *(const float4*)&W2[(kc + 1) * 256 + col0];
      float4 w2 = *(const float4*)&W2[(kc + 2) * 256 + col0];
      float4 w3 = *(const float4*)&W2[(kc + 3) * 256 + col0];
#pragma unroll
      for (int n = 0; n < 5; n++) {
        float4 iv = *(float4*)&s_t1[wv][nb0 + n][kc];
        acc[n][0] += iv.x * w0.x + iv.y * w1.x + iv.z * w2.x + iv.w * w3.x;
        acc[n][1] += iv.x * w0.y + iv.y * w1.y + iv.z * w2.y + iv.w * w3.y;
        acc[n][2] += iv.x * w0.z + iv.y * w1.z + iv.z * w2.z + iv.w * w3.z;
        acc[n][3] += iv.x * w0.w + iv.y * w1.w + iv.z * w2.w + iv.w * w3.w;
      }
    }
#pragma unroll
    for (int n = 0; n < 5; n++) {
      float s = fmaxf(acc[n][0] + b1v.x, 0.f) * w2v.x +
                fmaxf(acc[n][1] + b1v.y, 0.f) * w2v.y +
                fmaxf(acc[n][2] + b1v.z, 0.f) * w2v.z +
                fmaxf(acc[n][3] + b1v.w, 0.f) * w2v.w;
#pragma unroll
      for (int off = 32; off >= 1; off >>= 1) s += __shfl_xor(s, off);
      if (lane == 0) s_sim[wv][nb0 + n] = s + ab2v;
    }
  }
  __syncthreads();

  float mx = -3.402823466e38f;
#pragma unroll
  for (int n = 0; n < KNB; n++) mx = fmaxf(mx, s_sim[wv][n]);
  float sum = 0.f;
#pragma unroll
  for (int n = 0; n < KNB; n++) sum += expf(s_sim[wv][n] - mx);
  float inv = 1.f / sum;
  float o = 0.f;
  float sac = 0.f;
#pragma unroll
  for (int n = 0; n < KNB; n++) {
    int g = s_nb[wv][n];
    float an = expf(s_sim[wv][n] - mx) * inv;
    o += an * v[(size_t)g * 64 + lane];
    sac += an * t1[n];
  }
  float r = pb2[lane];
#pragma unroll 8
  for (int j = 0; j < 64; j++) r += RL(sac, j) * pw2[j * 64 + lane];
#undef RL
  xout[(size_t)i * 64 + lane] = o + r;
}

// ---------------------------------------------------------------------------
// K5a: parallel max-pool stage 1. R19's single-block-per-batch k_final ran
// at Occupancy 0.09% / 324 µs (2 CUs active). 128 blocks (2 batches x 64
// slices), each reduces 128 points -> partial max[64]. Float max is
// associative/commutative (finite inputs) -> bit-exact.
// ---------------------------------------------------------------------------
__global__ __launch_bounds__(256) void k_pool(const float* __restrict__ x,
                                              float* __restrict__ pmax) {
  __shared__ float red[4][64];
  int b = blockIdx.x >> 6, blk = blockIdx.x & 63;
  int tid = threadIdx.x;
  int c = tid & 63, pg = tid >> 6;
  int p0 = blk * 128;
  float mx = -3.402823466e38f;
  for (int p = pg; p < 128; p += 4)
    mx = fmaxf(mx, x[((size_t)b * NPTS + p0 + p) * 64 + c]);
  red[pg][c] = mx;
  __syncthreads();
  if (tid < 64)
    pmax[(size_t)blockIdx.x * 64 + c] =
        fmaxf(fmaxf(red[0][c], red[1][c]), fmaxf(red[2][c], red[3][c]));
}

// ---------------------------------------------------------------------------
// K5b: stage 2 — reduce 64 partials + fc1 + fc3 (tiny, 2 blocks).
// ---------------------------------------------------------------------------
__global__ __launch_bounds__(256) void k_final2(const float* __restrict__ pmax,
                                                const float* __restrict__ fc1w,
                                                const float* __restrict__ fc1b,
                                                const float* __restrict__ fc3w,
                                                const float* __restrict__ fc3b,
                                                float* __restrict__ out) {
  __shared__ float red[4][64];
  __shared__ float m[64];
  __shared__ float h1[32];
  int b = blockIdx.x;
  int tid = threadIdx.x;
  int c = tid & 63, pg = tid >> 6;
  float mx = -3.402823466e38f;
  for (int blk = pg; blk < 64; blk += 4)
    mx = fmaxf(mx, pmax[(size_t)(b * 64 + blk) * 64 + c]);
  red[pg][c] = mx;
  __syncthreads();
  if (tid < 64)
    m[c] = fmaxf(fmaxf(red[0][c], red[1][c]), fmaxf(red[2][c], red[3][c]));
  __syncthreads();
  if (tid < 32) {
    float a = fc1b[tid];
#pragma unroll 8
    for (int k = 0; k < 64; k++) a += m[k] * fc1w[k * 32 + tid];
    h1[tid] = fmaxf(a, 0.f);
  }
  __syncthreads();
  if (tid < 3) {
    float a = fc3b[tid];
#pragma unroll
    for (int k = 0; k < 32; k++) a += h1[k] * fc3w[k * 3 + tid];
    out[b * 3 + tid] = a;
  }
}

// ---------------------------------------------------------------------------
// Workspace (peak ~44.8 MB):
//   idx @ 0 (1.31MB) | ptsT @ 1.5MB (0.2MB) | W2 @ 1.75MB (64KB) |
//   c0 @ 1.82MB (1KB) | pmax @ 1.86MB (32KB) | v @ 2MB (4.2MB) |
//   kh @ 6.5MB (16.8MB) | qh @ 23.5MB (16.8MB) | act @ 40.5MB (4.2MB)
// ---------------------------------------------------------------------------
extern "C" void kernel_launch(void* const* d_in, const int* in_sizes, int n_in,
                              void* d_out, int out_size, void* d_ws,
                              size_t ws_size, hipStream_t stream) {
  const float* pts    = (const float*)d_in[0];
  const float* conv_w = (const float*)d_in[1];
  const float* conv_b = (const float*)d_in[2];
  const float* fc1w = (const float*)d_in[21];
  const float* fc1b = (const float*)d_in[22];
  const float* fc3w = (const float*)d_in[23];
  const float* fc3b = (const float*)d_in[24];
  float* outp = (float*)d_out;

  char* ws = (char*)d_ws;
  int*   idx  = (int*)  (ws);
  float* ptsT = (float*)(ws + (size_t)1536 * 1024);
  float* W2   = (float*)(ws + (size_t)1792 * 1024);
  float* c0   = (float*)(ws + (size_t)1862 * 1024);
  float* pmax = (float*)(ws + (size_t)1900 * 1024);
  float* v    = (float*)(ws + (size_t)2 * 1048576);
  float* kh   = (float*)(ws + (size_t)6656 * 1024);
  float* qh   = (float*)(ws + (size_t)24064 * 1024);
  float* act  = (float*)(ws + (size_t)41472 * 1024);

  k_pose<<<(TOTAL * 3 + 255) / 256, 256, 0, stream>>>(pts, ptsT);
  k_conv<<<(TOTAL * 64 + 255) / 256, 256, 0, stream>>>(pts, conv_w, conv_b, act);
  k_knn<<<TOTAL / 4, 256, 0, stream>>>(ptsT, pts, idx);

  for (int layer = 0; layer < 2; layer++) {
    int base = 3 + layer * 9;
    const float* qkvw = (const float*)d_in[base + 0];
    const float* pw1  = (const float*)d_in[base + 1];
    const float* pb1  = (const float*)d_in[base + 2];
    const float* pw2  = (const float*)d_in[base + 3];
    const float* pb2  = (const float*)d_in[base + 4];
    const float* aw1  = (const float*)d_in[base + 5];
    const float* ab1  = (const float*)d_in[base + 6];
    const float* aw2  = (const float*)d_in[base + 7];
    const float* ab2  = (const float*)d_in[base + 8];
    k_w2<<<65, 256, 0, stream>>>(pw2, pb2, aw1, W2, c0);
    k_pre<<<TOTAL / 4, 256, 0, stream>>>(act, qkvw, aw1, c0, v, kh, qh);
    k_attn<<<TOTAL / 4, 256, 0, stream>>>(
        pts, v, idx, kh, qh, pw1, pb1, pw2, pb2, W2, ab1, aw2, ab2, act);
  }
  k_pool<<<BATCH * 64, 256, 0, stream>>>(act, pmax);
  k_final2<<<BATCH, 256, 0, stream>>>(pmax, fc1w, fc1b, fc3w, fc3b, outp);
}